// Round 13
// baseline (359.990 us; speedup 1.0000x reference)
//
#include <hip/hip_runtime.h>
#include <cmath>

typedef __attribute__((ext_vector_type(8))) short  short8;
typedef __attribute__((ext_vector_type(4))) float  floatx4;
typedef __attribute__((ext_vector_type(8))) unsigned short ushort8;
typedef __attribute__((ext_vector_type(8))) unsigned char uchar8v;

// Accumulator slots spread 64B apart to avoid same-cacheline atomic serialization.
#define SLOT(i) ((i) * 16)
#define ACC_L1   0
#define ACC_MSE  1
#define ACC_ST0  2
#define ACC_ST1  3
#define ACC_SP0  4
#define ACC_SP1  5
#define ACC_HV   6
#define ACC_WV   7
#define ACC_EXP  8
#define ACC_SPAT 9
#define ACC_PERC 10
#define SSIM_SLOT(scale, cs, img) (256 + ((scale) * 12 + (cs) * 6 + (img)) * 16)

struct GW { float g[11]; };

__device__ __forceinline__ float waveSum(float v) {
#pragma unroll
  for (int o = 32; o > 0; o >>= 1) v += __shfl_down(v, o, 64);
  return v;
}

__device__ __forceinline__ float blockSum256(float v) {
  __shared__ float red[4];
  const int tid = threadIdx.x;
  v = waveSum(v);
  __syncthreads();
  if ((tid & 63) == 0) red[tid >> 6] = v;
  __syncthreads();
  return red[0] + red[1] + red[2] + red[3];
}

// pack 4 floats -> 4 OCP e4m3 bytes (HW cvt, RNE)
__device__ __forceinline__ unsigned int pk_fp8x4(float v0, float v1, float v2, float v3) {
  int p = __builtin_amdgcn_cvt_pk_fp8_f32(v0, v1, 0, false);
  p = __builtin_amdgcn_cvt_pk_fp8_f32(v2, v3, p, true);
  return (unsigned int)p;
}

// ---------------- small loss terms ----------------

__global__ __launch_bounds__(256) void basic_stats(const float* __restrict__ yt,
                                                   const float* __restrict__ yp,
                                                   float* __restrict__ acc) {
  const int N = 2 * 3 * 224 * 224;
  float l1 = 0.f, mse = 0.f, st0 = 0.f, st1 = 0.f, sp0 = 0.f, sp1 = 0.f, hv = 0.f, wv = 0.f;
  for (int idx = blockIdx.x * 256 + threadIdx.x; idx < N; idx += 256 * 256) {
    const float t = yt[idx], p = yp[idx];
    const float d = p - t;
    const float ad = fabsf(d);
    l1 += (ad < 1.f) ? 0.5f * d * d : ad - 0.5f;
    mse += d * d;
    if (idx < 3 * 224 * 224) { st0 += t; sp0 += p; } else { st1 += t; sp1 += p; }
    const int w = idx % 224;
    const int h = (idx / 224) % 224;
    if (h < 223) { const float dv = yp[idx + 224] - p; hv += dv * dv; }
    if (w < 223) { const float dw = yp[idx + 1] - p; wv += dw * dw; }
  }
  float s;
  s = blockSum256(l1);  if (threadIdx.x == 0) atomicAdd(acc + SLOT(ACC_L1), s);
  s = blockSum256(mse); if (threadIdx.x == 0) atomicAdd(acc + SLOT(ACC_MSE), s);
  s = blockSum256(st0); if (threadIdx.x == 0) atomicAdd(acc + SLOT(ACC_ST0), s);
  s = blockSum256(st1); if (threadIdx.x == 0) atomicAdd(acc + SLOT(ACC_ST1), s);
  s = blockSum256(sp0); if (threadIdx.x == 0) atomicAdd(acc + SLOT(ACC_SP0), s);
  s = blockSum256(sp1); if (threadIdx.x == 0) atomicAdd(acc + SLOT(ACC_SP1), s);
  s = blockSum256(hv);  if (threadIdx.x == 0) atomicAdd(acc + SLOT(ACC_HV), s);
  s = blockSum256(wv);  if (threadIdx.x == 0) atomicAdd(acc + SLOT(ACC_WV), s);
}

__global__ __launch_bounds__(256) void exposure_k(const float* __restrict__ yp,
                                                  float* __restrict__ acc) {
  const int blk = blockIdx.x;
  const int b = blk / 196;
  const int rem = blk - b * 196;
  const int py = rem / 14, px = rem - py * 14;
  float s = 0.f;
  for (int e = threadIdx.x; e < 768; e += 256) {
    const int c = e >> 8;
    const int rr = (e >> 4) & 15;
    const int cc = e & 15;
    s += yp[(((size_t)b * 3 + c) * 224 + py * 16 + rr) * 224 + px * 16 + cc];
  }
  const float t = blockSum256(s);
  if (threadIdx.x == 0) {
    const float m = t * (1.f / 768.f) - 0.6f;
    atomicAdd(acc + SLOT(ACC_EXP), m * m);
  }
}

__global__ __launch_bounds__(256) void pool4_lum_k(const float* __restrict__ yt,
                                                   const float* __restrict__ yp,
                                                   float* __restrict__ op,
                                                   float* __restrict__ ep) {
  const int idx = blockIdx.x * 256 + threadIdx.x;
  if (idx >= 2 * 56 * 56) return;
  const int b = idx / 3136;
  const int rem = idx - b * 3136;
  const int r = rem / 56, cl = rem - r * 56;
  float so = 0.f, se = 0.f;
  for (int c = 0; c < 3; ++c)
    for (int dy = 0; dy < 4; ++dy)
      for (int dx = 0; dx < 4; ++dx) {
        const size_t off = (((size_t)b * 3 + c) * 224 + (r * 4 + dy)) * 224 + cl * 4 + dx;
        so += yt[off]; se += yp[off];
      }
  op[idx] = so * (1.f / 48.f);
  ep[idx] = se * (1.f / 48.f);
}

__global__ __launch_bounds__(256) void spat_k(const float* __restrict__ op,
                                              const float* __restrict__ ep,
                                              float* __restrict__ acc) {
  const int idx = blockIdx.x * 256 + threadIdx.x;
  float v = 0.f;
  if (idx < 6272) {
    const int rem = idx % 3136;
    const int r = rem / 56, cl = rem - r * 56;
    const float oc = op[idx], ec = ep[idx];
    const float ol = (cl > 0)  ? op[idx - 1]  : 0.f;
    const float el = (cl > 0)  ? ep[idx - 1]  : 0.f;
    const float orr = (cl < 55) ? op[idx + 1]  : 0.f;
    const float er  = (cl < 55) ? ep[idx + 1]  : 0.f;
    const float ou = (r > 0)   ? op[idx - 56] : 0.f;
    const float eu = (r > 0)   ? ep[idx - 56] : 0.f;
    const float od = (r < 55)  ? op[idx + 56] : 0.f;
    const float ed = (r < 55)  ? ep[idx + 56] : 0.f;
    float d;
    d = (oc - ol) - (ec - el);   v += d * d;
    d = (oc - orr) - (ec - er);  v += d * d;
    d = (oc - ou) - (ec - eu);   v += d * d;
    d = (oc - od) - (ec - ed);   v += d * d;
  }
  const float t = blockSum256(v);
  if (threadIdx.x == 0) atomicAdd(acc + SLOT(ACC_SPAT), t);
}

// ---------------- MS-SSIM ----------------

// ALL pyramid levels (1..4) of X and Y in one launch, directly from originals:
// level s = mean over 2^s x 2^s window (avg-pool is associative; fp32 rounding
// delta irrelevant at 0.39 threshold). Layout per level: [6 imgs][h][h] at
// cumulative float offsets {0, 75264, 94080, 98784} (h = 112,56,28,14).
__global__ __launch_bounds__(256) void pyr_k(const float* __restrict__ yt,
                                             const float* __restrict__ yp,
                                             float* __restrict__ pX,
                                             float* __restrict__ pY) {
  const int PER = 99960;                 // floats per pyramid (all levels, 6 imgs)
  const int cum[5] = {0, 75264, 94080, 98784, 99960};
  const int idx = blockIdx.x * 256 + threadIdx.x;
  if (idx >= 2 * PER) return;
  const int half = idx / PER;            // 0 = X(yt), 1 = Y(yp)
  const int rem = idx - half * PER;
  int l = 0;
  while (rem >= cum[l + 1]) ++l;         // level-1..4 -> l = 0..3
  const int h = 112 >> l;
  const int k = 2 << l;                  // 2^(l+1)
  const int w = rem - cum[l];
  const int img = w / (h * h);
  const int p = w - img * (h * h);
  const int r = p / h, c = p - p / h * h;
  const float* src = (half ? yp : yt) + (size_t)img * 224 * 224 +
                     (size_t)(r * k) * 224 + c * k;
  float s = 0.f;
  for (int dy = 0; dy < k; ++dy)
    for (int dx = 0; dx < k; ++dx) s += src[(size_t)dy * 224 + dx];
  (half ? pY : pX)[rem] = s / (float)(k * k);
}

// ALL 5 scales' fused V+H gaussian + ssim/cs reduction in ONE launch.
// blockIdx.x indexed by cumulative tile counts {196,49,9,4,1} (16x16 out tiles),
// blockIdx.y = img. Body identical to the proven per-scale kernel.
struct SSArgs { const float* X[5]; const float* Y[5]; };
__global__ __launch_bounds__(256) void ssim_all_k(SSArgs a, float* __restrict__ acc, GW gw) {
  __shared__ float sX[26][27], sY[26][27];
  __shared__ float sV[5][16][27];
  const int ns[5] = {224, 112, 56, 28, 14};
  const int tl[5] = {14, 7, 3, 2, 1};
  const int cumB[6] = {0, 196, 245, 254, 258, 259};
  int sc = 0;
  while (blockIdx.x >= (unsigned)cumB[sc + 1]) ++sc;
  const int n = ns[sc];
  const int m = n - 10;
  const int tiles = tl[sc];
  const int tidx = blockIdx.x - cumB[sc];
  const int tid = threadIdx.x;
  const int img = blockIdx.y;
  const int ty0 = (tidx / tiles) * 16;
  const int tx0 = (tidx - (tidx / tiles) * tiles) * 16;
  const float* Xb = a.X[sc] + (size_t)img * n * n;
  const float* Yb = a.Y[sc] + (size_t)img * n * n;

  for (int e = tid; e < 26 * 26; e += 256) {
    const int r = e / 26, c = e - (e / 26) * 26;
    const int gy = ty0 + r, gx = tx0 + c;
    float xv = 0.f, yv = 0.f;
    if (gy < n && gx < n) {
      xv = Xb[(size_t)gy * n + gx];
      yv = Yb[(size_t)gy * n + gx];
    }
    sX[r][c] = xv; sY[r][c] = yv;
  }
  __syncthreads();

  for (int e = tid; e < 16 * 26; e += 256) {
    const int r = e / 26, c = e - (e / 26) * 26;
    float sx = 0.f, sy = 0.f, sxx = 0.f, syy = 0.f, sxy = 0.f;
#pragma unroll
    for (int t = 0; t < 11; ++t) {
      const float xv = sX[r + t][c];
      const float yv = sY[r + t][c];
      const float g = gw.g[t];
      sx += g * xv; sy += g * yv;
      sxx += g * xv * xv; syy += g * yv * yv; sxy += g * xv * yv;
    }
    sV[0][r][c] = sx; sV[1][r][c] = sy;
    sV[2][r][c] = sxx; sV[3][r][c] = syy; sV[4][r][c] = sxy;
  }
  __syncthreads();

  float sv = 0.f, cv = 0.f;
  {
    const int r = tid >> 4, c = tid & 15;
    if (ty0 + r < m && tx0 + c < m) {
      float mu1 = 0.f, mu2 = 0.f, e11 = 0.f, e22 = 0.f, e12 = 0.f;
#pragma unroll
      for (int t = 0; t < 11; ++t) {
        const float g = gw.g[t];
        mu1 += g * sV[0][r][c + t];
        mu2 += g * sV[1][r][c + t];
        e11 += g * sV[2][r][c + t];
        e22 += g * sV[3][r][c + t];
        e12 += g * sV[4][r][c + t];
      }
      const float C1 = 1e-4f, C2 = 9e-4f;
      const float s11 = e11 - mu1 * mu1;
      const float s22 = e22 - mu2 * mu2;
      const float s12 = e12 - mu1 * mu2;
      cv = (2.f * s12 + C2) / (s11 + s22 + C2);
      sv = ((2.f * mu1 * mu2 + C1) / (mu1 * mu1 + mu2 * mu2 + C1)) * cv;
    }
  }
  float t = blockSum256(sv);
  if (tid == 0) atomicAdd(acc + SSIM_SLOT(sc, 0, img), t);
  t = blockSum256(cv);
  if (tid == 0) atomicAdd(acc + SSIM_SLOT(sc, 1, img), t);
}

// ---------------- VGG (fp8 e4m3 path) ----------------

// fused prep: weight transform ([cout][tap][cin] fp8, pre-scaled x8) + border
// zeroing of all 6 batched padded NHWC fp8 buffers, one launch (disjoint ranges).
struct PrepArgs {
  const float* w[6];
  int co[6], ci[6];
  int wcum[7];
  unsigned char* zp[6];
  int zH[6], zC[6];
  int zcum[7];
};
__global__ __launch_bounds__(256) void prep_k(PrepArgs a, unsigned char* __restrict__ wdst) {
  const int idx = blockIdx.x * 256 + threadIdx.x;
  if (idx < a.wcum[6]) {
    int L = 0;
    while (idx >= a.wcum[L + 1]) ++L;
    const int r = idx - a.wcum[L];
    const int Cin = a.ci[L];
    const int cin = r % Cin;
    const int t = r / Cin;
    const int tap = t % 9;
    const int cout = t / 9;
    const float v = a.w[L][((size_t)cout * Cin + cin) * 9 + tap] * 8.0f;
    wdst[idx] = (unsigned char)(__builtin_amdgcn_cvt_pk_fp8_f32(v, v, 0, false) & 0xff);
    return;
  }
  const int zi = idx - a.wcum[6];
  if (zi >= a.zcum[6]) return;
  int b = 0;
  while (zi >= a.zcum[b + 1]) ++b;
  const int H = a.zH[b], C = a.zC[b];
  const int rowE = (H + 2) * C;
  const int per = 2 * rowE + 2 * H * C;
  int k = zi - a.zcum[b];
  const int img = k / per;
  const int k0 = k - img * per;
  size_t o;
  if (k0 < rowE) o = k0;
  else if (k0 < 2 * rowE) o = (size_t)(H + 1) * rowE + (k0 - rowE);
  else {
    const int kk = k0 - 2 * rowE;
    const int y = kk / (2 * C) + 1;
    const int r = kk % (2 * C);
    const int x = (r < C) ? 0 : (H + 1);
    const int c = (r < C) ? r : (r - C);
    o = (size_t)y * rowE + (size_t)x * C + c;
  }
  a.zp[b][(size_t)img * (H + 2) * rowE + o] = 0;
}

// layer1 batched: Cin=3 direct fp32 conv, 4 images -> padded NHWC fp8
__global__ __launch_bounds__(256) void conv1_k(
    const float* __restrict__ yt, const float* __restrict__ yp,
    const float* __restrict__ wt, const float* __restrict__ bias,
    unsigned char* __restrict__ out) {
  __shared__ float sIn[3][10][12];
  const int tx = threadIdx.x, ty = threadIdx.y, tz = threadIdx.z;
  const int tid = (tz << 6) | (ty << 3) | tx;
  const int img = blockIdx.z >> 2;
  const int zq = blockIdx.z & 3;
  const float* in = ((img >> 1) ? yp : yt) + (size_t)(img & 1) * 3 * 224 * 224;
  const int x0 = blockIdx.x << 3, y0 = blockIdx.y << 3;
  const int x = x0 + tx, y = y0 + ty;
  int wrow = (zq * 16 + tz * 4) * 27;
  wrow = __builtin_amdgcn_readfirstlane(wrow);

  for (int el = tid; el < 300; el += 256) {
    const int ci = el / 100;
    const int rem = el - ci * 100;
    const int r = rem / 10, cl = rem - r * 10;
    const int gy = y0 - 1 + r, gx = x0 - 1 + cl;
    float v = 0.f;
    if (gy >= 0 && gy < 224 && gx >= 0 && gx < 224)
      v = in[((size_t)ci * 224 + gy) * 224 + gx];
    sIn[ci][r][cl] = v;
  }
  __syncthreads();

  float a0 = 0.f, a1 = 0.f, a2 = 0.f, a3 = 0.f;
#pragma unroll
  for (int ci = 0; ci < 3; ++ci) {
    float xv[9];
#pragma unroll
    for (int ky = 0; ky < 3; ++ky)
#pragma unroll
      for (int kx = 0; kx < 3; ++kx)
        xv[ky * 3 + kx] = sIn[ci][ty + ky][tx + kx];
    const float* wp = wt + wrow + ci * 9;
#pragma unroll
    for (int k = 0; k < 9; ++k) {
      a0 = fmaf(xv[k], wp[k], a0);
      a1 = fmaf(xv[k], wp[27 + k], a1);
      a2 = fmaf(xv[k], wp[54 + k], a2);
      a3 = fmaf(xv[k], wp[81 + k], a3);
    }
  }
  const int coB = zq * 16 + tz * 4;
  const size_t o = (size_t)img * 226 * 226 * 64 + ((size_t)(y + 1) * 226 + (x + 1)) * 64 + coB;
  *(unsigned int*)(out + o) = pk_fp8x4(
      fmaxf(a0 + bias[coB + 0], 0.f), fmaxf(a1 + bias[coB + 1], 0.f),
      fmaxf(a2 + bias[coB + 2], 0.f), fmaxf(a3 + bias[coB + 3], 0.f));
}

// implicit-GEMM conv3x3, batched, fp8 e4m3 via mfma_f32_16x16x32_fp8_fp8.
// (R12 structure — delivered 414->348; index math identical to bf16 version.)
template<int CIN>
__global__ __launch_bounds__(256, 4) void conv_mfma(
    const unsigned char* __restrict__ in, const unsigned char* __restrict__ wtp,
    const float* __restrict__ bias, unsigned char* __restrict__ out,
    int W, int Cout, int rowsPI) {
  constexpr int NSLAB = CIN / 32;
  constexpr int ASTB = 304;
  constexpr int BSTB = 48;
  constexpr int NBRUN = 6 * 66;
  constexpr int NACH = 32 * 18;
  constexpr int NBCH = NBRUN * 2;
  __shared__ unsigned char As[32 * ASTB];
  __shared__ unsigned char Bs[NBRUN * BSTB];

  const int tid = threadIdx.x;
  const int lane = tid & 63;
  const int wave = tid >> 6;
  const int quad = lane >> 4;
  const int lr = lane & 15;
  const int img = blockIdx.y / rowsPI;
  const int y0 = (blockIdx.y - img * rowsPI) * 4;
  const int x0 = blockIdx.x * 64;
  const int cob = blockIdx.z * 32;
  const int Wp = W + 2;
  const int H = rowsPI * 4;
  const unsigned char* inI = in + (size_t)img * (H + 2) * Wp * CIN;
  unsigned char* outI = out + (size_t)img * (H + 2) * Wp * Cout;

  floatx4 acc[2][4];
#pragma unroll
  for (int m = 0; m < 2; ++m)
#pragma unroll
    for (int n = 0; n < 4; ++n) acc[m][n] = (floatx4){0.f, 0.f, 0.f, 0.f};

  const int abase = lr * ASTB + quad * 8;

  for (int s = 0; s < NSLAB; ++s) {
    __syncthreads();
#pragma unroll
    for (int i = 0; i < (NACH + 255) / 256; ++i) {
      const int ee = tid + i * 256;
      if (ee < NACH) {
        const int cout = ee / 18;
        const int rem = ee - cout * 18;
        const int tap = rem >> 1;
        const int part = rem & 1;
        const uint4 v = *(const uint4*)(wtp + ((size_t)(cob + cout) * 9 + tap) * CIN + s * 32 + part * 16);
        *(uint4*)(As + cout * ASTB + tap * 32 + part * 16) = v;
      }
    }
#pragma unroll
    for (int i = 0; i < (NBCH + 255) / 256; ++i) {
      const int ee = tid + i * 256;
      if (ee < NBCH) {
        const int part = ee & 1;
        const int run = ee >> 1;
        const int row = run / 66;
        const int px = run - row * 66;
        uint4 v = {0, 0, 0, 0};
        const int gx = x0 + px;
        if (gx < Wp)
          v = *(const uint4*)(inI + ((size_t)(y0 + row) * Wp + gx) * CIN + s * 32 + part * 16);
        *(uint4*)(Bs + run * BSTB + part * 16) = v;
      }
    }
    __syncthreads();

#pragma unroll
    for (int dy = 0; dy < 3; ++dy)
#pragma unroll
      for (int dx = 0; dx < 3; ++dx) {
        const int tap = dy * 3 + dx;
        const long af0 = *(const long*)(As + abase + tap * 32);
        const long af1 = *(const long*)(As + abase + 16 * ASTB + tap * 32);
        long bfr[4];
#pragma unroll
        for (int n = 0; n < 4; ++n)
          bfr[n] = *(const long*)(Bs + ((wave + dy) * 66 + n * 16 + lr + dx) * BSTB + quad * 8);
#pragma unroll
        for (int n = 0; n < 4; ++n) {
          acc[0][n] = __builtin_amdgcn_mfma_f32_16x16x32_fp8_fp8(af0, bfr[n], acc[0][n], 0, 0, 0);
          acc[1][n] = __builtin_amdgcn_mfma_f32_16x16x32_fp8_fp8(af1, bfr[n], acc[1][n], 0, 0, 0);
        }
      }
  }

#pragma unroll
  for (int m = 0; m < 2; ++m) {
    const int cb = cob + m * 16 + quad * 4;
#pragma unroll
    for (int n = 0; n < 4; ++n) {
      const int px = x0 + n * 16 + lr;
      if (px < W) {
        const float v0 = fmaxf(acc[m][n].x * 0.125f + bias[cb + 0], 0.f);
        const float v1 = fmaxf(acc[m][n].y * 0.125f + bias[cb + 1], 0.f);
        const float v2 = fmaxf(acc[m][n].z * 0.125f + bias[cb + 2], 0.f);
        const float v3 = fmaxf(acc[m][n].w * 0.125f + bias[cb + 3], 0.f);
        *(unsigned int*)(outI + ((size_t)(y0 + wave + 1) * Wp + px + 1) * Cout + cb) =
            pk_fp8x4(v0, v1, v2, v3);
      }
    }
  }
}

// batched 2x2 maxpool on padded NHWC fp8 (non-negative e4m3: byte max is exact)
__global__ __launch_bounds__(256) void pool_nhwc(const unsigned char* __restrict__ in,
                                                 unsigned char* __restrict__ out,
                                                 int Ho, int Wo, int C) {
  const int per = Ho * Wo * (C / 8);
  const int idx = blockIdx.x * 256 + threadIdx.x;
  if (idx >= 4 * per) return;
  const int img = idx / per;
  const int k = idx - img * per;
  const int c8 = k % (C / 8);
  const int p = k / (C / 8);
  const int x = p % Wo, y = p / Wo;
  const int Wi = 2 * Wo + 2;
  const unsigned char* ib = in + (size_t)img * (2 * Ho + 2) * Wi * C +
                            ((size_t)(2 * y + 1) * Wi + (2 * x + 1)) * C + c8 * 8;
  const uchar8v a = *(const uchar8v*)(ib);
  const uchar8v b = *(const uchar8v*)(ib + C);
  const uchar8v d = *(const uchar8v*)(ib + (size_t)Wi * C);
  const uchar8v e = *(const uchar8v*)(ib + (size_t)Wi * C + C);
  const uchar8v r = __builtin_elementwise_max(__builtin_elementwise_max(a, b),
                                              __builtin_elementwise_max(d, e));
  *(uchar8v*)(out + (size_t)img * (Ho + 2) * (Wo + 2) * C +
              ((size_t)(y + 1) * (Wo + 2) + x + 1) * C + c8 * 8) = r;
}

// perceptual over both batch pairs: F[img][58][58][256] fp8, pairs (0,2),(1,3)
#define FP8D(av, bv, J) { const float dd = __builtin_amdgcn_cvt_f32_fp8((av), (J)) - \
                                           __builtin_amdgcn_cvt_f32_fp8((bv), (J)); \
                          v = fmaf(dd, dd, v); }
__global__ __launch_bounds__(256) void perc_k(const unsigned char* __restrict__ f,
                                              float* __restrict__ acc) {
  const int PER = 56 * 56 * 256 / 8;
  const size_t STR = (size_t)58 * 58 * 256;
  float v = 0.f;
  for (int ch = blockIdx.x * 256 + threadIdx.x; ch < 2 * PER; ch += 256 * 256) {
    const int q = ch / PER;
    const int r = ch - q * PER;
    const int e = r * 8;
    const int c = e & 255;
    const int p = e >> 8;
    const int x = p % 56, y = p / 56;
    const size_t o = ((size_t)(y + 1) * 58 + x + 1) * 256 + c;
    const uint2 a = *(const uint2*)(f + q * STR + o);
    const uint2 b = *(const uint2*)(f + (q + 2) * STR + o);
    FP8D(a.x, b.x, 0) FP8D(a.x, b.x, 1) FP8D(a.x, b.x, 2) FP8D(a.x, b.x, 3)
    FP8D(a.y, b.y, 0) FP8D(a.y, b.y, 1) FP8D(a.y, b.y, 2) FP8D(a.y, b.y, 3)
  }
  const float t = blockSum256(v);
  if (threadIdx.x == 0) atomicAdd(acc + SLOT(ACC_PERC), t);
}

// ---------------- final combine ----------------
__global__ void final_k(const float* __restrict__ acc, float* __restrict__ out) {
  if (threadIdx.x != 0 || blockIdx.x != 0) return;
  const float NPIX = 2.f * 3.f * 224.f * 224.f;
  const float l1 = acc[SLOT(ACC_L1)] / NPIX;
  const float mse = acc[SLOT(ACC_MSE)] / NPIX;
  const float psnr = 40.f + 10.f * log10f(mse);
  const float cm = 1.f / (3.f * 224.f * 224.f);
  const float color = 0.5f * (fabsf(acc[SLOT(ACC_ST0)] - acc[SLOT(ACC_SP0)]) +
                              fabsf(acc[SLOT(ACC_ST1)] - acc[SLOT(ACC_SP1)])) * cm;
  const float ill = acc[SLOT(ACC_HV)] / 669.f + acc[SLOT(ACC_WV)] / 448.f;
  const float expl = acc[SLOT(ACC_EXP)] / 392.f;
  const float spat = acc[SLOT(ACC_SPAT)] / 6272.f;
  const float perc = acc[SLOT(ACC_PERC)] / 1605632.f;
  const float wms[5] = {0.0448f, 0.2856f, 0.3001f, 0.2363f, 0.1333f};
  const int ns[5] = {214, 102, 46, 18, 4};
  float msum = 0.f;
  for (int img = 0; img < 6; ++img) {
    float prod = 1.f;
    for (int s = 0; s < 5; ++s) {
      const float denom = (float)(ns[s] * ns[s]);
      float v = (s == 4) ? acc[SSIM_SLOT(s, 0, img)] / denom
                         : acc[SSIM_SLOT(s, 1, img)] / denom;
      v = fmaxf(v, 0.f);
      prod *= powf(v, wms[s]);
    }
    msum += prod;
  }
  const float msssim = msum / 6.f;
  out[0] = l1 + 0.06f * perc + 0.0083f * psnr + 0.25f * color +
           0.5f * (1.f - msssim) + 0.1f * expl + 0.1f * ill + 0.1f * spat;
}

extern "C" void kernel_launch(void* const* d_in, const int* in_sizes, int n_in,
                              void* d_out, int out_size, void* d_ws, size_t ws_size,
                              hipStream_t stream) {
  const float* yt = (const float*)d_in[0];
  const float* yp = (const float*)d_in[1];
  const float* W7[7]; const float* B7[7];
  for (int i = 0; i < 7; ++i) {
    W7[i] = (const float*)d_in[2 + 2 * i];
    B7[i] = (const float*)d_in[3 + 2 * i];
  }

  char* ws = (char*)d_ws;
  float* acc = (float*)ws;
  size_t off = 16384;
  float* op = (float*)(ws + off); off += 2 * 3136 * 4;
  float* ep = (float*)(ws + off); off += 2 * 3136 * 4;
  auto align256 = [&]() { off = (off + 255) & ~(size_t)255; };
  align256(); unsigned char* C1  = (unsigned char*)(ws + off); off += (size_t)4 * 226 * 226 * 64;
  align256(); unsigned char* T0  = (unsigned char*)(ws + off); off += (size_t)4 * 226 * 226 * 64;
  align256(); unsigned char* Pl1 = (unsigned char*)(ws + off); off += (size_t)4 * 114 * 114 * 64;
  align256(); unsigned char* C3  = (unsigned char*)(ws + off); off += (size_t)4 * 114 * 114 * 128;
  align256(); unsigned char* Pl2 = (unsigned char*)(ws + off); off += (size_t)4 * 58 * 58 * 128;
  align256(); unsigned char* C5  = (unsigned char*)(ws + off); off += (size_t)4 * 58 * 58 * 256;
  align256(); unsigned char* C6  = (unsigned char*)(ws + off); off += (size_t)4 * 58 * 58 * 256;
  align256(); unsigned char* F   = (unsigned char*)(ws + off); off += (size_t)4 * 58 * 58 * 256;
  align256(); unsigned char* WT  = (unsigned char*)(ws + off); off += (size_t)1732608;
  align256(); float* pyrX = (float*)(ws + off); off += (size_t)99960 * 4;
  align256(); float* pyrY = (float*)(ws + off); off += (size_t)99960 * 4;
  if (ws_size < off) return;

  GW gw;
  {
    double vv[11]; double s = 0.0;
    for (int i = 0; i < 11; ++i) { const double c = i - 5.0; vv[i] = exp(-(c * c) / 4.5); s += vv[i]; }
    for (int i = 0; i < 11; ++i) gw.g[i] = (float)(vv[i] / s);
  }

  hipMemsetAsync(acc, 0, 16384, stream);

  // fused prep: weight transform + all border zeroing (one launch)
  const int co[7] = {64, 64, 128, 128, 256, 256, 256};
  const int ci[7] = {3, 64, 64, 128, 128, 256, 256};
  PrepArgs pa;
  size_t wtOff[7];
  {
    int e = 0;
    for (int i = 1; i < 7; ++i) {
      pa.w[i - 1] = W7[i]; pa.co[i - 1] = co[i]; pa.ci[i - 1] = ci[i];
      pa.wcum[i - 1] = e; wtOff[i] = (size_t)e; e += co[i] * 9 * ci[i];
    }
    pa.wcum[6] = e;
    unsigned char* bufs[6] = {C1, Pl1, C3, Pl2, C5, C6};
    const int hh[6] = {224, 112, 112, 56, 56, 56};
    const int cc[6] = {64, 64, 128, 128, 256, 256};
    int z = 0;
    for (int i = 0; i < 6; ++i) {
      pa.zp[i] = bufs[i]; pa.zH[i] = hh[i]; pa.zC[i] = cc[i];
      pa.zcum[i] = z;
      z += 4 * (2 * (hh[i] + 2) * cc[i] + 2 * hh[i] * cc[i]);
    }
    pa.zcum[6] = z;
    const int tot = pa.wcum[6] + z;
    prep_k<<<(tot + 255) / 256, 256, 0, stream>>>(pa, WT);
  }

  basic_stats<<<256, 256, 0, stream>>>(yt, yp, acc);
  exposure_k<<<392, 256, 0, stream>>>(yp, acc);
  pool4_lum_k<<<25, 256, 0, stream>>>(yt, yp, op, ep);
  spat_k<<<25, 256, 0, stream>>>(op, ep, acc);

  // MS-SSIM: 2 launches total (pyramid from originals, then all 5 scales)
  pyr_k<<<(2 * 99960 + 255) / 256, 256, 0, stream>>>(yt, yp, pyrX, pyrY);
  {
    SSArgs sa;
    sa.X[0] = yt; sa.Y[0] = yp;
    const int cum[4] = {0, 75264, 94080, 98784};
    for (int s = 1; s < 5; ++s) { sa.X[s] = pyrX + cum[s - 1]; sa.Y[s] = pyrY + cum[s - 1]; }
    ssim_all_k<<<dim3(259, 6), 256, 0, stream>>>(sa, acc, gw);
  }

  // VGG19[:16] in fp8, all 4 images per dispatch.
  conv1_k<<<dim3(28, 28, 16), dim3(8, 8, 4), 0, stream>>>(yt, yp, W7[0], B7[0], C1);
  conv_mfma<64> <<<dim3(4, 4 * 56, 2), 256, 0, stream>>>(C1,  WT + wtOff[1], B7[1], T0, 224, 64, 56);
  pool_nhwc<<<(4 * 112 * 112 * 8 + 255) / 256, 256, 0, stream>>>(T0, Pl1, 112, 112, 64);
  conv_mfma<64> <<<dim3(2, 4 * 28, 4), 256, 0, stream>>>(Pl1, WT + wtOff[2], B7[2], C3, 112, 128, 28);
  conv_mfma<128><<<dim3(2, 4 * 28, 4), 256, 0, stream>>>(C3,  WT + wtOff[3], B7[3], T0, 112, 128, 28);
  pool_nhwc<<<(4 * 56 * 56 * 16 + 255) / 256, 256, 0, stream>>>(T0, Pl2, 56, 56, 128);
  conv_mfma<128><<<dim3(1, 4 * 14, 8), 256, 0, stream>>>(Pl2, WT + wtOff[4], B7[4], C5, 56, 256, 14);
  conv_mfma<256><<<dim3(1, 4 * 14, 8), 256, 0, stream>>>(C5,  WT + wtOff[5], B7[5], C6, 56, 256, 14);
  conv_mfma<256><<<dim3(1, 4 * 14, 8), 256, 0, stream>>>(C6,  WT + wtOff[6], B7[6], F,  56, 256, 14);
  perc_k<<<256, 256, 0, stream>>>(F, acc);

  final_k<<<1, 64, 0, stream>>>(acc, (float*)d_out);
}

// Round 14
// 346.123 us; speedup vs baseline: 1.0401x; 1.0401x over previous
//
#include <hip/hip_runtime.h>
#include <cmath>

typedef __attribute__((ext_vector_type(8))) short  short8;
typedef __attribute__((ext_vector_type(4))) float  floatx4;
typedef __attribute__((ext_vector_type(8))) unsigned short ushort8;
typedef __attribute__((ext_vector_type(8))) unsigned char uchar8v;

// Accumulator slots spread 64B apart to avoid same-cacheline atomic serialization.
#define SLOT(i) ((i) * 16)
#define ACC_L1   0
#define ACC_MSE  1
#define ACC_ST0  2
#define ACC_ST1  3
#define ACC_SP0  4
#define ACC_SP1  5
#define ACC_HV   6
#define ACC_WV   7
#define ACC_EXP  8
#define ACC_SPAT 9
#define ACC_PERC 10
#define SSIM_SLOT(scale, cs, img) (256 + ((scale) * 12 + (cs) * 6 + (img)) * 16)

struct GW { float g[11]; };

__device__ __forceinline__ float waveSum(float v) {
#pragma unroll
  for (int o = 32; o > 0; o >>= 1) v += __shfl_down(v, o, 64);
  return v;
}

__device__ __forceinline__ float blockSum256(float v) {
  __shared__ float red[4];
  const int tid = threadIdx.x;
  v = waveSum(v);
  __syncthreads();
  if ((tid & 63) == 0) red[tid >> 6] = v;
  __syncthreads();
  return red[0] + red[1] + red[2] + red[3];
}

// pack 4 floats -> 4 OCP e4m3 bytes (HW cvt, RNE)
__device__ __forceinline__ unsigned int pk_fp8x4(float v0, float v1, float v2, float v3) {
  int p = __builtin_amdgcn_cvt_pk_fp8_f32(v0, v1, 0, false);
  p = __builtin_amdgcn_cvt_pk_fp8_f32(v2, v3, p, true);
  return (unsigned int)p;
}

// ---------------- small loss terms ----------------

__global__ __launch_bounds__(256) void basic_stats(const float* __restrict__ yt,
                                                   const float* __restrict__ yp,
                                                   float* __restrict__ acc) {
  const int N = 2 * 3 * 224 * 224;
  float l1 = 0.f, mse = 0.f, st0 = 0.f, st1 = 0.f, sp0 = 0.f, sp1 = 0.f, hv = 0.f, wv = 0.f;
  for (int idx = blockIdx.x * 256 + threadIdx.x; idx < N; idx += 256 * 256) {
    const float t = yt[idx], p = yp[idx];
    const float d = p - t;
    const float ad = fabsf(d);
    l1 += (ad < 1.f) ? 0.5f * d * d : ad - 0.5f;
    mse += d * d;
    if (idx < 3 * 224 * 224) { st0 += t; sp0 += p; } else { st1 += t; sp1 += p; }
    const int w = idx % 224;
    const int h = (idx / 224) % 224;
    if (h < 223) { const float dv = yp[idx + 224] - p; hv += dv * dv; }
    if (w < 223) { const float dw = yp[idx + 1] - p; wv += dw * dw; }
  }
  float s;
  s = blockSum256(l1);  if (threadIdx.x == 0) atomicAdd(acc + SLOT(ACC_L1), s);
  s = blockSum256(mse); if (threadIdx.x == 0) atomicAdd(acc + SLOT(ACC_MSE), s);
  s = blockSum256(st0); if (threadIdx.x == 0) atomicAdd(acc + SLOT(ACC_ST0), s);
  s = blockSum256(st1); if (threadIdx.x == 0) atomicAdd(acc + SLOT(ACC_ST1), s);
  s = blockSum256(sp0); if (threadIdx.x == 0) atomicAdd(acc + SLOT(ACC_SP0), s);
  s = blockSum256(sp1); if (threadIdx.x == 0) atomicAdd(acc + SLOT(ACC_SP1), s);
  s = blockSum256(hv);  if (threadIdx.x == 0) atomicAdd(acc + SLOT(ACC_HV), s);
  s = blockSum256(wv);  if (threadIdx.x == 0) atomicAdd(acc + SLOT(ACC_WV), s);
}

__global__ __launch_bounds__(256) void exposure_k(const float* __restrict__ yp,
                                                  float* __restrict__ acc) {
  const int blk = blockIdx.x;
  const int b = blk / 196;
  const int rem = blk - b * 196;
  const int py = rem / 14, px = rem - py * 14;
  float s = 0.f;
  for (int e = threadIdx.x; e < 768; e += 256) {
    const int c = e >> 8;
    const int rr = (e >> 4) & 15;
    const int cc = e & 15;
    s += yp[(((size_t)b * 3 + c) * 224 + py * 16 + rr) * 224 + px * 16 + cc];
  }
  const float t = blockSum256(s);
  if (threadIdx.x == 0) {
    const float m = t * (1.f / 768.f) - 0.6f;
    atomicAdd(acc + SLOT(ACC_EXP), m * m);
  }
}

__global__ __launch_bounds__(256) void pool4_lum_k(const float* __restrict__ yt,
                                                   const float* __restrict__ yp,
                                                   float* __restrict__ op,
                                                   float* __restrict__ ep) {
  const int idx = blockIdx.x * 256 + threadIdx.x;
  if (idx >= 2 * 56 * 56) return;
  const int b = idx / 3136;
  const int rem = idx - b * 3136;
  const int r = rem / 56, cl = rem - r * 56;
  float so = 0.f, se = 0.f;
  for (int c = 0; c < 3; ++c)
    for (int dy = 0; dy < 4; ++dy)
      for (int dx = 0; dx < 4; ++dx) {
        const size_t off = (((size_t)b * 3 + c) * 224 + (r * 4 + dy)) * 224 + cl * 4 + dx;
        so += yt[off]; se += yp[off];
      }
  op[idx] = so * (1.f / 48.f);
  ep[idx] = se * (1.f / 48.f);
}

__global__ __launch_bounds__(256) void spat_k(const float* __restrict__ op,
                                              const float* __restrict__ ep,
                                              float* __restrict__ acc) {
  const int idx = blockIdx.x * 256 + threadIdx.x;
  float v = 0.f;
  if (idx < 6272) {
    const int rem = idx % 3136;
    const int r = rem / 56, cl = rem - r * 56;
    const float oc = op[idx], ec = ep[idx];
    const float ol = (cl > 0)  ? op[idx - 1]  : 0.f;
    const float el = (cl > 0)  ? ep[idx - 1]  : 0.f;
    const float orr = (cl < 55) ? op[idx + 1]  : 0.f;
    const float er  = (cl < 55) ? ep[idx + 1]  : 0.f;
    const float ou = (r > 0)   ? op[idx - 56] : 0.f;
    const float eu = (r > 0)   ? ep[idx - 56] : 0.f;
    const float od = (r < 55)  ? op[idx + 56] : 0.f;
    const float ed = (r < 55)  ? ep[idx + 56] : 0.f;
    float d;
    d = (oc - ol) - (ec - el);   v += d * d;
    d = (oc - orr) - (ec - er);  v += d * d;
    d = (oc - ou) - (ec - eu);   v += d * d;
    d = (oc - od) - (ec - ed);   v += d * d;
  }
  const float t = blockSum256(v);
  if (threadIdx.x == 0) atomicAdd(acc + SLOT(ACC_SPAT), t);
}

// ---------------- MS-SSIM (R12 structure: per-scale fused kernel + down2) ----------------

__global__ __launch_bounds__(256) void ssim_fused_k(const float* __restrict__ X,
                                                    const float* __restrict__ Y,
                                                    float* __restrict__ acc,
                                                    int n, int scale, int tiles, GW gw) {
  __shared__ float sX[26][27], sY[26][27];
  __shared__ float sV[5][16][27];
  const int m = n - 10;
  const int tid = threadIdx.x;
  const int img = blockIdx.y;
  const int ty0 = (blockIdx.x / tiles) * 16;
  const int tx0 = (blockIdx.x - (blockIdx.x / tiles) * tiles) * 16;
  const float* Xb = X + (size_t)img * n * n;
  const float* Yb = Y + (size_t)img * n * n;

  for (int e = tid; e < 26 * 26; e += 256) {
    const int r = e / 26, c = e - (e / 26) * 26;
    const int gy = ty0 + r, gx = tx0 + c;
    float xv = 0.f, yv = 0.f;
    if (gy < n && gx < n) {
      xv = Xb[(size_t)gy * n + gx];
      yv = Yb[(size_t)gy * n + gx];
    }
    sX[r][c] = xv; sY[r][c] = yv;
  }
  __syncthreads();

  for (int e = tid; e < 16 * 26; e += 256) {
    const int r = e / 26, c = e - (e / 26) * 26;
    float sx = 0.f, sy = 0.f, sxx = 0.f, syy = 0.f, sxy = 0.f;
#pragma unroll
    for (int t = 0; t < 11; ++t) {
      const float xv = sX[r + t][c];
      const float yv = sY[r + t][c];
      const float g = gw.g[t];
      sx += g * xv; sy += g * yv;
      sxx += g * xv * xv; syy += g * yv * yv; sxy += g * xv * yv;
    }
    sV[0][r][c] = sx; sV[1][r][c] = sy;
    sV[2][r][c] = sxx; sV[3][r][c] = syy; sV[4][r][c] = sxy;
  }
  __syncthreads();

  float sv = 0.f, cv = 0.f;
  {
    const int r = tid >> 4, c = tid & 15;
    if (ty0 + r < m && tx0 + c < m) {
      float mu1 = 0.f, mu2 = 0.f, e11 = 0.f, e22 = 0.f, e12 = 0.f;
#pragma unroll
      for (int t = 0; t < 11; ++t) {
        const float g = gw.g[t];
        mu1 += g * sV[0][r][c + t];
        mu2 += g * sV[1][r][c + t];
        e11 += g * sV[2][r][c + t];
        e22 += g * sV[3][r][c + t];
        e12 += g * sV[4][r][c + t];
      }
      const float C1 = 1e-4f, C2 = 9e-4f;
      const float s11 = e11 - mu1 * mu1;
      const float s22 = e22 - mu2 * mu2;
      const float s12 = e12 - mu1 * mu2;
      cv = (2.f * s12 + C2) / (s11 + s22 + C2);
      sv = ((2.f * mu1 * mu2 + C1) / (mu1 * mu1 + mu2 * mu2 + C1)) * cv;
    }
  }
  float t = blockSum256(sv);
  if (tid == 0) atomicAdd(acc + SSIM_SLOT(scale, 0, img), t);
  t = blockSum256(cv);
  if (tid == 0) atomicAdd(acc + SSIM_SLOT(scale, 1, img), t);
}

__global__ __launch_bounds__(256) void down2_k(const float* __restrict__ X,
                                               const float* __restrict__ Y,
                                               float* __restrict__ OX,
                                               float* __restrict__ OY, int n) {
  const int h = n >> 1;
  const int total = 12 * h * h;
  const int idx = blockIdx.x * 256 + threadIdx.x;
  if (idx >= total) return;
  int j = idx / (h * h);
  const int rem = idx - j * (h * h);
  const float* src; float* dst;
  if (j < 6) { src = X; dst = OX; } else { src = Y; dst = OY; j -= 6; }
  const int r = rem / h, cl = rem - r * h;
  const float* xb = src + (size_t)j * n * n + (size_t)(2 * r) * n + 2 * cl;
  dst[(size_t)j * h * h + rem] = 0.25f * (xb[0] + xb[1] + xb[n] + xb[n + 1]);
}

// ---------------- VGG (fp8 e4m3 path) ----------------

// fused prep: weight transform ([cout][tap][cin] fp8, pre-scaled x8) + border
// zeroing of all 6 batched padded NHWC fp8 buffers, one launch (disjoint ranges).
struct PrepArgs {
  const float* w[6];
  int co[6], ci[6];
  int wcum[7];
  unsigned char* zp[6];
  int zH[6], zC[6];
  int zcum[7];
};
__global__ __launch_bounds__(256) void prep_k(PrepArgs a, unsigned char* __restrict__ wdst) {
  const int idx = blockIdx.x * 256 + threadIdx.x;
  if (idx < a.wcum[6]) {
    int L = 0;
    while (idx >= a.wcum[L + 1]) ++L;
    const int r = idx - a.wcum[L];
    const int Cin = a.ci[L];
    const int cin = r % Cin;
    const int t = r / Cin;
    const int tap = t % 9;
    const int cout = t / 9;
    const float v = a.w[L][((size_t)cout * Cin + cin) * 9 + tap] * 8.0f;
    wdst[idx] = (unsigned char)(__builtin_amdgcn_cvt_pk_fp8_f32(v, v, 0, false) & 0xff);
    return;
  }
  const int zi = idx - a.wcum[6];
  if (zi >= a.zcum[6]) return;
  int b = 0;
  while (zi >= a.zcum[b + 1]) ++b;
  const int H = a.zH[b], C = a.zC[b];
  const int rowE = (H + 2) * C;
  const int per = 2 * rowE + 2 * H * C;
  int k = zi - a.zcum[b];
  const int img = k / per;
  const int k0 = k - img * per;
  size_t o;
  if (k0 < rowE) o = k0;
  else if (k0 < 2 * rowE) o = (size_t)(H + 1) * rowE + (k0 - rowE);
  else {
    const int kk = k0 - 2 * rowE;
    const int y = kk / (2 * C) + 1;
    const int r = kk % (2 * C);
    const int x = (r < C) ? 0 : (H + 1);
    const int c = (r < C) ? r : (r - C);
    o = (size_t)y * rowE + (size_t)x * C + c;
  }
  a.zp[b][(size_t)img * (H + 2) * rowE + o] = 0;
}

// layer1 batched: Cin=3 direct fp32 conv, 4 images -> padded NHWC fp8
__global__ __launch_bounds__(256) void conv1_k(
    const float* __restrict__ yt, const float* __restrict__ yp,
    const float* __restrict__ wt, const float* __restrict__ bias,
    unsigned char* __restrict__ out) {
  __shared__ float sIn[3][10][12];
  const int tx = threadIdx.x, ty = threadIdx.y, tz = threadIdx.z;
  const int tid = (tz << 6) | (ty << 3) | tx;
  const int img = blockIdx.z >> 2;
  const int zq = blockIdx.z & 3;
  const float* in = ((img >> 1) ? yp : yt) + (size_t)(img & 1) * 3 * 224 * 224;
  const int x0 = blockIdx.x << 3, y0 = blockIdx.y << 3;
  const int x = x0 + tx, y = y0 + ty;
  int wrow = (zq * 16 + tz * 4) * 27;
  wrow = __builtin_amdgcn_readfirstlane(wrow);

  for (int el = tid; el < 300; el += 256) {
    const int ci = el / 100;
    const int rem = el - ci * 100;
    const int r = rem / 10, cl = rem - r * 10;
    const int gy = y0 - 1 + r, gx = x0 - 1 + cl;
    float v = 0.f;
    if (gy >= 0 && gy < 224 && gx >= 0 && gx < 224)
      v = in[((size_t)ci * 224 + gy) * 224 + gx];
    sIn[ci][r][cl] = v;
  }
  __syncthreads();

  float a0 = 0.f, a1 = 0.f, a2 = 0.f, a3 = 0.f;
#pragma unroll
  for (int ci = 0; ci < 3; ++ci) {
    float xv[9];
#pragma unroll
    for (int ky = 0; ky < 3; ++ky)
#pragma unroll
      for (int kx = 0; kx < 3; ++kx)
        xv[ky * 3 + kx] = sIn[ci][ty + ky][tx + kx];
    const float* wp = wt + wrow + ci * 9;
#pragma unroll
    for (int k = 0; k < 9; ++k) {
      a0 = fmaf(xv[k], wp[k], a0);
      a1 = fmaf(xv[k], wp[27 + k], a1);
      a2 = fmaf(xv[k], wp[54 + k], a2);
      a3 = fmaf(xv[k], wp[81 + k], a3);
    }
  }
  const int coB = zq * 16 + tz * 4;
  const size_t o = (size_t)img * 226 * 226 * 64 + ((size_t)(y + 1) * 226 + (x + 1)) * 64 + coB;
  *(unsigned int*)(out + o) = pk_fp8x4(
      fmaxf(a0 + bias[coB + 0], 0.f), fmaxf(a1 + bias[coB + 1], 0.f),
      fmaxf(a2 + bias[coB + 2], 0.f), fmaxf(a3 + bias[coB + 3], 0.f));
}

// implicit-GEMM conv3x3, batched, fp8 e4m3 via mfma_f32_16x16x32_fp8_fp8.
// (R12 structure — delivered 414->348; index math identical to bf16 version.)
template<int CIN>
__global__ __launch_bounds__(256, 4) void conv_mfma(
    const unsigned char* __restrict__ in, const unsigned char* __restrict__ wtp,
    const float* __restrict__ bias, unsigned char* __restrict__ out,
    int W, int Cout, int rowsPI) {
  constexpr int NSLAB = CIN / 32;
  constexpr int ASTB = 304;
  constexpr int BSTB = 48;
  constexpr int NBRUN = 6 * 66;
  constexpr int NACH = 32 * 18;
  constexpr int NBCH = NBRUN * 2;
  __shared__ unsigned char As[32 * ASTB];
  __shared__ unsigned char Bs[NBRUN * BSTB];

  const int tid = threadIdx.x;
  const int lane = tid & 63;
  const int wave = tid >> 6;
  const int quad = lane >> 4;
  const int lr = lane & 15;
  const int img = blockIdx.y / rowsPI;
  const int y0 = (blockIdx.y - img * rowsPI) * 4;
  const int x0 = blockIdx.x * 64;
  const int cob = blockIdx.z * 32;
  const int Wp = W + 2;
  const int H = rowsPI * 4;
  const unsigned char* inI = in + (size_t)img * (H + 2) * Wp * CIN;
  unsigned char* outI = out + (size_t)img * (H + 2) * Wp * Cout;

  floatx4 acc[2][4];
#pragma unroll
  for (int m = 0; m < 2; ++m)
#pragma unroll
    for (int n = 0; n < 4; ++n) acc[m][n] = (floatx4){0.f, 0.f, 0.f, 0.f};

  const int abase = lr * ASTB + quad * 8;

  for (int s = 0; s < NSLAB; ++s) {
    __syncthreads();
#pragma unroll
    for (int i = 0; i < (NACH + 255) / 256; ++i) {
      const int ee = tid + i * 256;
      if (ee < NACH) {
        const int cout = ee / 18;
        const int rem = ee - cout * 18;
        const int tap = rem >> 1;
        const int part = rem & 1;
        const uint4 v = *(const uint4*)(wtp + ((size_t)(cob + cout) * 9 + tap) * CIN + s * 32 + part * 16);
        *(uint4*)(As + cout * ASTB + tap * 32 + part * 16) = v;
      }
    }
#pragma unroll
    for (int i = 0; i < (NBCH + 255) / 256; ++i) {
      const int ee = tid + i * 256;
      if (ee < NBCH) {
        const int part = ee & 1;
        const int run = ee >> 1;
        const int row = run / 66;
        const int px = run - row * 66;
        uint4 v = {0, 0, 0, 0};
        const int gx = x0 + px;
        if (gx < Wp)
          v = *(const uint4*)(inI + ((size_t)(y0 + row) * Wp + gx) * CIN + s * 32 + part * 16);
        *(uint4*)(Bs + run * BSTB + part * 16) = v;
      }
    }
    __syncthreads();

#pragma unroll
    for (int dy = 0; dy < 3; ++dy)
#pragma unroll
      for (int dx = 0; dx < 3; ++dx) {
        const int tap = dy * 3 + dx;
        const long af0 = *(const long*)(As + abase + tap * 32);
        const long af1 = *(const long*)(As + abase + 16 * ASTB + tap * 32);
        long bfr[4];
#pragma unroll
        for (int n = 0; n < 4; ++n)
          bfr[n] = *(const long*)(Bs + ((wave + dy) * 66 + n * 16 + lr + dx) * BSTB + quad * 8);
#pragma unroll
        for (int n = 0; n < 4; ++n) {
          acc[0][n] = __builtin_amdgcn_mfma_f32_16x16x32_fp8_fp8(af0, bfr[n], acc[0][n], 0, 0, 0);
          acc[1][n] = __builtin_amdgcn_mfma_f32_16x16x32_fp8_fp8(af1, bfr[n], acc[1][n], 0, 0, 0);
        }
      }
  }

#pragma unroll
  for (int m = 0; m < 2; ++m) {
    const int cb = cob + m * 16 + quad * 4;
#pragma unroll
    for (int n = 0; n < 4; ++n) {
      const int px = x0 + n * 16 + lr;
      if (px < W) {
        const float v0 = fmaxf(acc[m][n].x * 0.125f + bias[cb + 0], 0.f);
        const float v1 = fmaxf(acc[m][n].y * 0.125f + bias[cb + 1], 0.f);
        const float v2 = fmaxf(acc[m][n].z * 0.125f + bias[cb + 2], 0.f);
        const float v3 = fmaxf(acc[m][n].w * 0.125f + bias[cb + 3], 0.f);
        *(unsigned int*)(outI + ((size_t)(y0 + wave + 1) * Wp + px + 1) * Cout + cb) =
            pk_fp8x4(v0, v1, v2, v3);
      }
    }
  }
}

// batched 2x2 maxpool on padded NHWC fp8 (non-negative e4m3: byte max is exact)
__global__ __launch_bounds__(256) void pool_nhwc(const unsigned char* __restrict__ in,
                                                 unsigned char* __restrict__ out,
                                                 int Ho, int Wo, int C) {
  const int per = Ho * Wo * (C / 8);
  const int idx = blockIdx.x * 256 + threadIdx.x;
  if (idx >= 4 * per) return;
  const int img = idx / per;
  const int k = idx - img * per;
  const int c8 = k % (C / 8);
  const int p = k / (C / 8);
  const int x = p % Wo, y = p / Wo;
  const int Wi = 2 * Wo + 2;
  const unsigned char* ib = in + (size_t)img * (2 * Ho + 2) * Wi * C +
                            ((size_t)(2 * y + 1) * Wi + (2 * x + 1)) * C + c8 * 8;
  const uchar8v a = *(const uchar8v*)(ib);
  const uchar8v b = *(const uchar8v*)(ib + C);
  const uchar8v d = *(const uchar8v*)(ib + (size_t)Wi * C);
  const uchar8v e = *(const uchar8v*)(ib + (size_t)Wi * C + C);
  const uchar8v r = __builtin_elementwise_max(__builtin_elementwise_max(a, b),
                                              __builtin_elementwise_max(d, e));
  *(uchar8v*)(out + (size_t)img * (Ho + 2) * (Wo + 2) * C +
              ((size_t)(y + 1) * (Wo + 2) + x + 1) * C + c8 * 8) = r;
}

// perceptual over both batch pairs: F[img][58][58][256] fp8, pairs (0,2),(1,3)
#define FP8D(av, bv, J) { const float dd = __builtin_amdgcn_cvt_f32_fp8((av), (J)) - \
                                           __builtin_amdgcn_cvt_f32_fp8((bv), (J)); \
                          v = fmaf(dd, dd, v); }
__global__ __launch_bounds__(256) void perc_k(const unsigned char* __restrict__ f,
                                              float* __restrict__ acc) {
  const int PER = 56 * 56 * 256 / 8;
  const size_t STR = (size_t)58 * 58 * 256;
  float v = 0.f;
  for (int ch = blockIdx.x * 256 + threadIdx.x; ch < 2 * PER; ch += 256 * 256) {
    const int q = ch / PER;
    const int r = ch - q * PER;
    const int e = r * 8;
    const int c = e & 255;
    const int p = e >> 8;
    const int x = p % 56, y = p / 56;
    const size_t o = ((size_t)(y + 1) * 58 + x + 1) * 256 + c;
    const uint2 a = *(const uint2*)(f + q * STR + o);
    const uint2 b = *(const uint2*)(f + (q + 2) * STR + o);
    FP8D(a.x, b.x, 0) FP8D(a.x, b.x, 1) FP8D(a.x, b.x, 2) FP8D(a.x, b.x, 3)
    FP8D(a.y, b.y, 0) FP8D(a.y, b.y, 1) FP8D(a.y, b.y, 2) FP8D(a.y, b.y, 3)
  }
  const float t = blockSum256(v);
  if (threadIdx.x == 0) atomicAdd(acc + SLOT(ACC_PERC), t);
}

// ---------------- final combine ----------------
__global__ void final_k(const float* __restrict__ acc, float* __restrict__ out) {
  if (threadIdx.x != 0 || blockIdx.x != 0) return;
  const float NPIX = 2.f * 3.f * 224.f * 224.f;
  const float l1 = acc[SLOT(ACC_L1)] / NPIX;
  const float mse = acc[SLOT(ACC_MSE)] / NPIX;
  const float psnr = 40.f + 10.f * log10f(mse);
  const float cm = 1.f / (3.f * 224.f * 224.f);
  const float color = 0.5f * (fabsf(acc[SLOT(ACC_ST0)] - acc[SLOT(ACC_SP0)]) +
                              fabsf(acc[SLOT(ACC_ST1)] - acc[SLOT(ACC_SP1)])) * cm;
  const float ill = acc[SLOT(ACC_HV)] / 669.f + acc[SLOT(ACC_WV)] / 448.f;
  const float expl = acc[SLOT(ACC_EXP)] / 392.f;
  const float spat = acc[SLOT(ACC_SPAT)] / 6272.f;
  const float perc = acc[SLOT(ACC_PERC)] / 1605632.f;
  const float wms[5] = {0.0448f, 0.2856f, 0.3001f, 0.2363f, 0.1333f};
  const int ns[5] = {214, 102, 46, 18, 4};
  float msum = 0.f;
  for (int img = 0; img < 6; ++img) {
    float prod = 1.f;
    for (int s = 0; s < 5; ++s) {
      const float denom = (float)(ns[s] * ns[s]);
      float v = (s == 4) ? acc[SSIM_SLOT(s, 0, img)] / denom
                         : acc[SSIM_SLOT(s, 1, img)] / denom;
      v = fmaxf(v, 0.f);
      prod *= powf(v, wms[s]);
    }
    msum += prod;
  }
  const float msssim = msum / 6.f;
  out[0] = l1 + 0.06f * perc + 0.0083f * psnr + 0.25f * color +
           0.5f * (1.f - msssim) + 0.1f * expl + 0.1f * ill + 0.1f * spat;
}

extern "C" void kernel_launch(void* const* d_in, const int* in_sizes, int n_in,
                              void* d_out, int out_size, void* d_ws, size_t ws_size,
                              hipStream_t stream) {
  const float* yt = (const float*)d_in[0];
  const float* yp = (const float*)d_in[1];
  const float* W7[7]; const float* B7[7];
  for (int i = 0; i < 7; ++i) {
    W7[i] = (const float*)d_in[2 + 2 * i];
    B7[i] = (const float*)d_in[3 + 2 * i];
  }

  char* ws = (char*)d_ws;
  float* acc = (float*)ws;
  size_t off = 16384;
  float* op = (float*)(ws + off); off += 2 * 3136 * 4;
  float* ep = (float*)(ws + off); off += 2 * 3136 * 4;
  auto align256 = [&]() { off = (off + 255) & ~(size_t)255; };
  align256(); unsigned char* C1  = (unsigned char*)(ws + off); off += (size_t)4 * 226 * 226 * 64;
  align256(); unsigned char* T0  = (unsigned char*)(ws + off); off += (size_t)4 * 226 * 226 * 64;
  align256(); unsigned char* Pl1 = (unsigned char*)(ws + off); off += (size_t)4 * 114 * 114 * 64;
  align256(); unsigned char* C3  = (unsigned char*)(ws + off); off += (size_t)4 * 114 * 114 * 128;
  align256(); unsigned char* Pl2 = (unsigned char*)(ws + off); off += (size_t)4 * 58 * 58 * 128;
  align256(); unsigned char* C5  = (unsigned char*)(ws + off); off += (size_t)4 * 58 * 58 * 256;
  align256(); unsigned char* C6  = (unsigned char*)(ws + off); off += (size_t)4 * 58 * 58 * 256;
  align256(); unsigned char* F   = (unsigned char*)(ws + off); off += (size_t)4 * 58 * 58 * 256;
  align256(); unsigned char* WT  = (unsigned char*)(ws + off); off += (size_t)1732608;
  align256(); float* pyrX = (float*)(ws + off); off += (size_t)100000 * 4;
  align256(); float* pyrY = (float*)(ws + off); off += (size_t)100000 * 4;
  if (ws_size < off) return;

  GW gw;
  {
    double vv[11]; double s = 0.0;
    for (int i = 0; i < 11; ++i) { const double c = i - 5.0; vv[i] = exp(-(c * c) / 4.5); s += vv[i]; }
    for (int i = 0; i < 11; ++i) gw.g[i] = (float)(vv[i] / s);
  }

  hipMemsetAsync(acc, 0, 16384, stream);

  // fused prep: weight transform + all border zeroing (one launch)
  const int co[7] = {64, 64, 128, 128, 256, 256, 256};
  const int ci[7] = {3, 64, 64, 128, 128, 256, 256};
  PrepArgs pa;
  size_t wtOff[7];
  {
    int e = 0;
    for (int i = 1; i < 7; ++i) {
      pa.w[i - 1] = W7[i]; pa.co[i - 1] = co[i]; pa.ci[i - 1] = ci[i];
      pa.wcum[i - 1] = e; wtOff[i] = (size_t)e; e += co[i] * 9 * ci[i];
    }
    pa.wcum[6] = e;
    unsigned char* bufs[6] = {C1, Pl1, C3, Pl2, C5, C6};
    const int hh[6] = {224, 112, 112, 56, 56, 56};
    const int cc[6] = {64, 64, 128, 128, 256, 256};
    int z = 0;
    for (int i = 0; i < 6; ++i) {
      pa.zp[i] = bufs[i]; pa.zH[i] = hh[i]; pa.zC[i] = cc[i];
      pa.zcum[i] = z;
      z += 4 * (2 * (hh[i] + 2) * cc[i] + 2 * hh[i] * cc[i]);
    }
    pa.zcum[6] = z;
    const int tot = pa.wcum[6] + z;
    prep_k<<<(tot + 255) / 256, 256, 0, stream>>>(pa, WT);
  }

  basic_stats<<<256, 256, 0, stream>>>(yt, yp, acc);
  exposure_k<<<392, 256, 0, stream>>>(yp, acc);
  pool4_lum_k<<<25, 256, 0, stream>>>(yt, yp, op, ep);
  spat_k<<<25, 256, 0, stream>>>(op, ep, acc);

  // MS-SSIM (R12 structure): per-scale fused kernel + cascaded down2
  const int dims[5] = {224, 112, 56, 28, 14};
  const int pyrOff[4] = {0, 75264, 94080, 98784};
  const float* Xs = yt; const float* Ys = yp;
  for (int s = 0; s < 5; ++s) {
    const int n = dims[s], m = n - 10;
    const int tiles = (m + 15) / 16;
    dim3 g(tiles * tiles, 6);
    ssim_fused_k<<<g, 256, 0, stream>>>(Xs, Ys, acc, n, s, tiles, gw);
    if (s < 4) {
      const int hn = n >> 1;
      float* nx = pyrX + pyrOff[s];
      float* ny = pyrY + pyrOff[s];
      down2_k<<<(12 * hn * hn + 255) / 256, 256, 0, stream>>>(Xs, Ys, nx, ny, n);
      Xs = nx; Ys = ny;
    }
  }

  // VGG19[:16] in fp8, all 4 images per dispatch.
  conv1_k<<<dim3(28, 28, 16), dim3(8, 8, 4), 0, stream>>>(yt, yp, W7[0], B7[0], C1);
  conv_mfma<64> <<<dim3(4, 4 * 56, 2), 256, 0, stream>>>(C1,  WT + wtOff[1], B7[1], T0, 224, 64, 56);
  pool_nhwc<<<(4 * 112 * 112 * 8 + 255) / 256, 256, 0, stream>>>(T0, Pl1, 112, 112, 64);
  conv_mfma<64> <<<dim3(2, 4 * 28, 4), 256, 0, stream>>>(Pl1, WT + wtOff[2], B7[2], C3, 112, 128, 28);
  conv_mfma<128><<<dim3(2, 4 * 28, 4), 256, 0, stream>>>(C3,  WT + wtOff[3], B7[3], T0, 112, 128, 28);
  pool_nhwc<<<(4 * 56 * 56 * 16 + 255) / 256, 256, 0, stream>>>(T0, Pl2, 56, 56, 128);
  conv_mfma<128><<<dim3(1, 4 * 14, 8), 256, 0, stream>>>(Pl2, WT + wtOff[4], B7[4], C5, 56, 256, 14);
  conv_mfma<256><<<dim3(1, 4 * 14, 8), 256, 0, stream>>>(C5,  WT + wtOff[5], B7[5], C6, 56, 256, 14);
  conv_mfma<256><<<dim3(1, 4 * 14, 8), 256, 0, stream>>>(C6,  WT + wtOff[6], B7[6], F,  56, 256, 14);
  perc_k<<<256, 256, 0, stream>>>(F, acc);

  final_k<<<1, 64, 0, stream>>>(acc, (float*)d_out);
}